// Round 6
// baseline (237.680 us; speedup 1.0000x reference)
//
#include <hip/hip_runtime.h>

// Problem constants (from reference): B=8, C=16, N=512, E=1024
#define Bn 8
#define Cn 16
#define Nn 512
#define En 1024
#define QPB 65536  // float4-quads per (b, c) plane: N*N/4
#define HSZ 2048   // hash slots (2x E)
#define MBLK 1024  // main_pass blocks (128 per batch)

// clang native vector types (required by __builtin_nontemporal_load)
typedef float fx4 __attribute__((ext_vector_type(4)));
typedef int   ix4 __attribute__((ext_vector_type(4)));

// *** MEASUREMENT ROUND ***: main_pass is launched 3x (idempotent ws stores).
// dur_us delta vs R5 (198.8us) = 2 x main_pass steady-state duration.
// No other change vs R5.

__global__ __launch_bounds__(256, 4) void main_pass(const fx4* __restrict__ adj4,
                                                    const ix4* __restrict__ mask4,
                                                    float* __restrict__ ws) {
    const int bid = blockIdx.x;
    const int b   = bid >> 7;                          // 128 blocks/batch
    const int q0  = ((bid & 127) << 9) + threadIdx.x;  // quad A; quad B = q0+256
    const fx4* base = adj4 + (size_t)b * (size_t)(Cn * QPB) + q0;

    fx4 x0a, x0b;
    float s0 = 0.f, s1 = 0.f, s2 = 0.f, s3 = 0.f;
    float s4 = 0.f, s5 = 0.f, s6 = 0.f, s7 = 0.f;

#pragma unroll
    for (int c = 0; c < 8; ++c) {
        fx4 va = __builtin_nontemporal_load(&base[(size_t)c * QPB]);
        fx4 vb = __builtin_nontemporal_load(&base[(size_t)c * QPB + 256]);
        if (c == 0) { x0a = va; x0b = vb; }
        s0 += __expf(va.x); s1 += __expf(va.y); s2 += __expf(va.z); s3 += __expf(va.w);
        s4 += __expf(vb.x); s5 += __expf(vb.y); s6 += __expf(vb.z); s7 += __expf(vb.w);
    }
#pragma unroll
    for (int c = 8; c < 16; ++c) {
        fx4 va = __builtin_nontemporal_load(&base[(size_t)c * QPB]);
        fx4 vb = __builtin_nontemporal_load(&base[(size_t)c * QPB + 256]);
        s0 += __expf(va.x); s1 += __expf(va.y); s2 += __expf(va.z); s3 += __expf(va.w);
        s4 += __expf(vb.x); s5 += __expf(vb.y); s6 += __expf(vb.z); s7 += __expf(vb.w);
    }

    const ix4 ma = __builtin_nontemporal_load(&mask4[(size_t)b * QPB + q0]);
    const ix4 mb = __builtin_nontemporal_load(&mask4[(size_t)b * QPB + q0 + 256]);

    float S = 0.f, cnt = 0.f;
    if (ma.x) { S += __logf(s0) - x0a.x; cnt += 1.f; }
    if (ma.y) { S += __logf(s1) - x0a.y; cnt += 1.f; }
    if (ma.z) { S += __logf(s2) - x0a.z; cnt += 1.f; }
    if (ma.w) { S += __logf(s3) - x0a.w; cnt += 1.f; }
    if (mb.x) { S += __logf(s4) - x0b.x; cnt += 1.f; }
    if (mb.y) { S += __logf(s5) - x0b.y; cnt += 1.f; }
    if (mb.z) { S += __logf(s6) - x0b.z; cnt += 1.f; }
    if (mb.w) { S += __logf(s7) - x0b.w; cnt += 1.f; }

#pragma unroll
    for (int d = 32; d; d >>= 1) {
        S   += __shfl_down(S, d, 64);
        cnt += __shfl_down(cnt, d, 64);
    }
    __shared__ float sh[8];
    const int wave = threadIdx.x >> 6;
    if ((threadIdx.x & 63) == 0) { sh[wave] = S; sh[4 + wave] = cnt; }
    __syncthreads();
    if (threadIdx.x == 0) {
        ws[bid * 2 + 0] = sh[0] + sh[1] + sh[2] + sh[3];
        ws[bid * 2 + 1] = sh[4] + sh[5] + sh[6] + sh[7];
    }
}

__global__ __launch_bounds__(1024) void edge_pass(const float* __restrict__ adj,
                                                  const int* __restrict__ mask,
                                                  const int* __restrict__ eidx,
                                                  const int* __restrict__ eattr,
                                                  const float* __restrict__ ws,
                                                  float* __restrict__ out) {
    const int b = blockIdx.x;
    const int e = threadIdx.x;

    __shared__ int   keys[HSZ];
    __shared__ int   maxe[HSZ];
    __shared__ float shS[16], shC[16], shV[16];

    keys[e]      = -1;
    keys[e + En] = -1;
    maxe[e]      = -1;
    maxe[e + En] = -1;

    float Sp = 0.f, Cp = 0.f;
    if (e < 128) {
        Sp = ws[(b * 128 + e) * 2 + 0];
        Cp = ws[(b * 128 + e) * 2 + 1];
    }
    const int2 rc   = ((const int2*)eidx)[b * En + e];
    const int  attr = eattr[b * En + e];
    const int  key  = (rc.x << 9) | rc.y;

#pragma unroll
    for (int d = 32; d; d >>= 1) {
        Sp += __shfl_down(Sp, d, 64);
        Cp += __shfl_down(Cp, d, 64);
    }
    const int wave = e >> 6;
    if ((e & 63) == 0) { shS[wave] = Sp; shC[wave] = Cp; }
    __syncthreads();

    unsigned h = ((unsigned)key * 2654435761u) >> 21;
    int slot = -1;
    for (;;) {
        int prev = atomicCAS(&keys[h], -1, key);
        if (prev == -1 || prev == key) { slot = (int)h; break; }
        h = (h + 1) & (HSZ - 1);
    }
    atomicMax(&maxe[slot], e);
    __syncthreads();

    float val = 0.f;
    if (maxe[slot] == e && attr != 0 &&
        mask[(size_t)b * Nn * Nn + rc.x * Nn + rc.y] != 0) {
        const size_t p0 = (((size_t)b * Cn) * Nn + rc.x) * Nn + rc.y;
        val = adj[p0] - adj[p0 + (size_t)attr * Nn * Nn];
    }
#pragma unroll
    for (int d = 32; d; d >>= 1) val += __shfl_down(val, d, 64);
    if ((e & 63) == 0) shV[wave] = val;
    __syncthreads();

    if (e == 0) {
        float S = shS[0] + shS[1];
        float C = shC[0] + shC[1];
        float corr = 0.f;
#pragma unroll
        for (int w = 0; w < 16; ++w) corr += shV[w];
        const float t = (S + corr) / fmaxf(C, 1.0f);
        atomicAdd(out, t * (1.0f / (float)Bn));
    }
}

extern "C" void kernel_launch(void* const* d_in, const int* in_sizes, int n_in,
                              void* d_out, int out_size, void* d_ws, size_t ws_size,
                              hipStream_t stream) {
    const float* adj  = (const float*)d_in[0];  // [B, C, N, N] fp32
    const int*   mask = (const int*)d_in[1];    // [B, N, N] bool -> int32
    const int*   eidx = (const int*)d_in[2];    // [B, E, 2] int32
    const int*   eatt = (const int*)d_in[3];    // [B, E] int32
    float*       out  = (float*)d_out;          // scalar fp32
    float*       ws   = (float*)d_ws;

    (void)hipMemsetAsync(d_out, 0, sizeof(float), stream);
    // 3x launch: idempotent; dur delta vs R5 = 2x main_pass duration.
    main_pass<<<dim3(MBLK), dim3(256), 0, stream>>>(
        (const fx4*)adj, (const ix4*)mask, ws);
    main_pass<<<dim3(MBLK), dim3(256), 0, stream>>>(
        (const fx4*)adj, (const ix4*)mask, ws);
    main_pass<<<dim3(MBLK), dim3(256), 0, stream>>>(
        (const fx4*)adj, (const ix4*)mask, ws);
    edge_pass<<<dim3(Bn), dim3(En), 0, stream>>>(adj, mask, eidx, eatt, ws, out);
}

// Round 7
// 196.611 us; speedup vs baseline: 1.2089x; 1.2089x over previous
//
#include <hip/hip_runtime.h>

// Problem constants (from reference): B=8, C=16, N=512, E=1024
#define Bn 8
#define Cn 16
#define Nn 512
#define En 1024
#define QPB 65536  // float4-quads per (b, c) plane: N*N/4
#define HSZ 2048   // hash slots (2x E)
#define MBLK 1024  // main_pass blocks (128 per batch)

// clang native vector types (required by __builtin_nontemporal_load)
typedef float fx4 __attribute__((ext_vector_type(4)));
typedef int   ix4 __attribute__((ext_vector_type(4)));

// ws layout (float): ws[blk*2+0]=S partial, ws[blk*2+1]=count partial.
// Written unconditionally by main_pass -> no zero-init needed.
// main_pass block 0 also zeroes out[0] (replaces a separate memset dispatch;
// safe: main_pass completes before edge_pass starts on the same stream).
//
// Measured (R6 3x-launch probe): main_pass ~19.5us steady-state = 142 MB at
// ~7.3 TB/s effective (L3-assisted) -- at the memory roofline.

__global__ __launch_bounds__(256, 4) void main_pass(const fx4* __restrict__ adj4,
                                                    const ix4* __restrict__ mask4,
                                                    float* __restrict__ ws,
                                                    float* __restrict__ out) {
    const int bid = blockIdx.x;
    if (bid == 0 && threadIdx.x == 0) out[0] = 0.f;

    const int b   = bid >> 7;                          // 128 blocks/batch
    const int q0  = ((bid & 127) << 9) + threadIdx.x;  // quad A; quad B = q0+256
    const fx4* base = adj4 + (size_t)b * (size_t)(Cn * QPB) + q0;

    fx4 x0a, x0b;
    float s0 = 0.f, s1 = 0.f, s2 = 0.f, s3 = 0.f;
    float s4 = 0.f, s5 = 0.f, s6 = 0.f, s7 = 0.f;

#pragma unroll
    for (int c = 0; c < 8; ++c) {
        fx4 va = __builtin_nontemporal_load(&base[(size_t)c * QPB]);
        fx4 vb = __builtin_nontemporal_load(&base[(size_t)c * QPB + 256]);
        if (c == 0) { x0a = va; x0b = vb; }
        s0 += __expf(va.x); s1 += __expf(va.y); s2 += __expf(va.z); s3 += __expf(va.w);
        s4 += __expf(vb.x); s5 += __expf(vb.y); s6 += __expf(vb.z); s7 += __expf(vb.w);
    }
#pragma unroll
    for (int c = 8; c < 16; ++c) {
        fx4 va = __builtin_nontemporal_load(&base[(size_t)c * QPB]);
        fx4 vb = __builtin_nontemporal_load(&base[(size_t)c * QPB + 256]);
        s0 += __expf(va.x); s1 += __expf(va.y); s2 += __expf(va.z); s3 += __expf(va.w);
        s4 += __expf(vb.x); s5 += __expf(vb.y); s6 += __expf(vb.z); s7 += __expf(vb.w);
    }

    const ix4 ma = __builtin_nontemporal_load(&mask4[(size_t)b * QPB + q0]);
    const ix4 mb = __builtin_nontemporal_load(&mask4[(size_t)b * QPB + q0 + 256]);

    float S = 0.f, cnt = 0.f;
    if (ma.x) { S += __logf(s0) - x0a.x; cnt += 1.f; }
    if (ma.y) { S += __logf(s1) - x0a.y; cnt += 1.f; }
    if (ma.z) { S += __logf(s2) - x0a.z; cnt += 1.f; }
    if (ma.w) { S += __logf(s3) - x0a.w; cnt += 1.f; }
    if (mb.x) { S += __logf(s4) - x0b.x; cnt += 1.f; }
    if (mb.y) { S += __logf(s5) - x0b.y; cnt += 1.f; }
    if (mb.z) { S += __logf(s6) - x0b.z; cnt += 1.f; }
    if (mb.w) { S += __logf(s7) - x0b.w; cnt += 1.f; }

#pragma unroll
    for (int d = 32; d; d >>= 1) {
        S   += __shfl_down(S, d, 64);
        cnt += __shfl_down(cnt, d, 64);
    }
    __shared__ float sh[8];
    const int wave = threadIdx.x >> 6;
    if ((threadIdx.x & 63) == 0) { sh[wave] = S; sh[4 + wave] = cnt; }
    __syncthreads();
    if (threadIdx.x == 0) {
        ws[bid * 2 + 0] = sh[0] + sh[1] + sh[2] + sh[3];
        ws[bid * 2 + 1] = sh[4] + sh[5] + sh[6] + sh[7];
    }
}

// ---------------------------------------------------------------------------
// Pass 2 (fused finalize): reduce this batch's 128 main_pass partials, then
// edge corrections via O(E) LDS hash dedup (last-writer-wins), then
// out += ((S_b + corr_b) / max(cnt_b,1)) / B.
// ---------------------------------------------------------------------------
__global__ __launch_bounds__(1024) void edge_pass(const float* __restrict__ adj,
                                                  const int* __restrict__ mask,
                                                  const int* __restrict__ eidx,
                                                  const int* __restrict__ eattr,
                                                  const float* __restrict__ ws,
                                                  float* __restrict__ out) {
    const int b = blockIdx.x;
    const int e = threadIdx.x;

    __shared__ int   keys[HSZ];
    __shared__ int   maxe[HSZ];
    __shared__ float shS[16], shC[16], shV[16];

    keys[e]      = -1;
    keys[e + En] = -1;
    maxe[e]      = -1;
    maxe[e + En] = -1;

    // ---- partial-sum reduction (threads 0..127 carry data) ----
    float Sp = 0.f, Cp = 0.f;
    if (e < 128) {
        Sp = ws[(b * 128 + e) * 2 + 0];
        Cp = ws[(b * 128 + e) * 2 + 1];
    }
    // coalesced edge loads (issue before barrier)
    const int2 rc   = ((const int2*)eidx)[b * En + e];
    const int  attr = eattr[b * En + e];
    const int  key  = (rc.x << 9) | rc.y;

#pragma unroll
    for (int d = 32; d; d >>= 1) {
        Sp += __shfl_down(Sp, d, 64);
        Cp += __shfl_down(Cp, d, 64);
    }
    const int wave = e >> 6;
    if ((e & 63) == 0) { shS[wave] = Sp; shC[wave] = Cp; }
    __syncthreads();   // also covers keys/maxe init

    // ---- hash insert: claim slot, last-writer-wins via atomicMax ----
    unsigned h = ((unsigned)key * 2654435761u) >> 21;
    int slot = -1;
    for (;;) {
        int prev = atomicCAS(&keys[h], -1, key);
        if (prev == -1 || prev == key) { slot = (int)h; break; }
        h = (h + 1) & (HSZ - 1);
    }
    atomicMax(&maxe[slot], e);
    __syncthreads();

    float val = 0.f;
    if (maxe[slot] == e && attr != 0 &&
        mask[(size_t)b * Nn * Nn + rc.x * Nn + rc.y] != 0) {
        const size_t p0 = (((size_t)b * Cn) * Nn + rc.x) * Nn + rc.y;
        val = adj[p0] - adj[p0 + (size_t)attr * Nn * Nn];
    }
#pragma unroll
    for (int d = 32; d; d >>= 1) val += __shfl_down(val, d, 64);
    if ((e & 63) == 0) shV[wave] = val;
    __syncthreads();

    if (e == 0) {
        float S = shS[0] + shS[1];             // only waves 0-1 held partials
        float C = shC[0] + shC[1];
        float corr = 0.f;
#pragma unroll
        for (int w = 0; w < 16; ++w) corr += shV[w];
        const float t = (S + corr) / fmaxf(C, 1.0f);
        atomicAdd(out, t * (1.0f / (float)Bn));
    }
}

extern "C" void kernel_launch(void* const* d_in, const int* in_sizes, int n_in,
                              void* d_out, int out_size, void* d_ws, size_t ws_size,
                              hipStream_t stream) {
    const float* adj  = (const float*)d_in[0];  // [B, C, N, N] fp32
    const int*   mask = (const int*)d_in[1];    // [B, N, N] bool -> int32
    const int*   eidx = (const int*)d_in[2];    // [B, E, 2] int32
    const int*   eatt = (const int*)d_in[3];    // [B, E] int32
    float*       out  = (float*)d_out;          // scalar fp32
    float*       ws   = (float*)d_ws;

    main_pass<<<dim3(MBLK), dim3(256), 0, stream>>>(
        (const fx4*)adj, (const ix4*)mask, ws, out);
    edge_pass<<<dim3(Bn), dim3(En), 0, stream>>>(adj, mask, eidx, eatt, ws, out);
}